// Round 12
// baseline (65.659 us; speedup 1.0000x reference)
//
#include <hip/hip_runtime.h>
#include <stdint.h>

#define BB 64
#define NC 1000       // customers per instance
#define KC 10         // clusters
#define MAXR 512      // routes per instance upper bound (realistic max ~140)
#define WPB 16        // blocks per instance in fused kernel
#define GPI (WPB * 16)  // 16-lane NN groups per instance = 256

__host__ __device__ inline void threefry2x32(uint32_t k0, uint32_t k1,
                                             uint32_t x0, uint32_t x1,
                                             uint32_t* o0, uint32_t* o1) {
  uint32_t k2 = k0 ^ k1 ^ 0x1BD11BDAu;
  x0 += k0; x1 += k1;
#define TF_R(R) { x0 += x1; x1 = (x1 << (R)) | (x1 >> (32 - (R))); x1 ^= x0; }
  TF_R(13) TF_R(15) TF_R(26) TF_R(6)
  x0 += k1; x1 += k2 + 1u;
  TF_R(17) TF_R(29) TF_R(16) TF_R(24)
  x0 += k2; x1 += k0 + 2u;
  TF_R(13) TF_R(15) TF_R(26) TF_R(6)
  x0 += k0; x1 += k1 + 3u;
  TF_R(17) TF_R(29) TF_R(16) TF_R(24)
  x0 += k1; x1 += k2 + 4u;
  TF_R(13) TF_R(15) TF_R(26) TF_R(6)
  x0 += k2; x1 += k0 + 5u;
#undef TF_R
  *o0 = x0; *o1 = x1;
}

__device__ inline uint32_t rand_bits(uint32_t ks0, uint32_t ks1, uint32_t p) {
  uint32_t a, b; threefry2x32(ks0, ks1, 0u, p, &a, &b); return b;
}

// ---- 16-lane DPP helpers (each 16-lane group = one DPP row; call sites are
// ---- convergent -> all source lanes active). CTRLs: 0xB1 lane^1, 0x4E lane^2,
// ---- 0x141 half-mirror (xor4 effective), 0x140 mirror (xor8 effective).
template <int CTRL>
__device__ __forceinline__ void dpp_min_step(unsigned long long& comb,
                                             float& x, float& y) {
  int lo = (int)(uint32_t)comb;
  int hi = (int)(uint32_t)(comb >> 32);
  int olo = __builtin_amdgcn_update_dpp(lo, lo, CTRL, 0xf, 0xf, false);
  int ohi = __builtin_amdgcn_update_dpp(hi, hi, CTRL, 0xf, 0xf, false);
  int oxi = __builtin_amdgcn_update_dpp(__float_as_int(x), __float_as_int(x),
                                        CTRL, 0xf, 0xf, false);
  int oyi = __builtin_amdgcn_update_dpp(__float_as_int(y), __float_as_int(y),
                                        CTRL, 0xf, 0xf, false);
  unsigned long long o =
      ((unsigned long long)(uint32_t)ohi << 32) | (uint32_t)olo;
  if (o < comb) { comb = o; x = __int_as_float(oxi); y = __int_as_float(oyi); }
}

template <int CTRL>
__device__ __forceinline__ void dpp_max_step(unsigned long long& pk, float& x) {
  int lo = (int)(uint32_t)pk;
  int hi = (int)(uint32_t)(pk >> 32);
  int olo = __builtin_amdgcn_update_dpp(lo, lo, CTRL, 0xf, 0xf, false);
  int ohi = __builtin_amdgcn_update_dpp(hi, hi, CTRL, 0xf, 0xf, false);
  int oxi = __builtin_amdgcn_update_dpp(__float_as_int(x), __float_as_int(x),
                                        CTRL, 0xf, 0xf, false);
  unsigned long long o =
      ((unsigned long long)(uint32_t)ohi << 32) | (uint32_t)olo;
  if (o > pk) { pk = o; x = __int_as_float(oxi); }
}

template <int CTRL>
__device__ __forceinline__ float dpp_fmax(float x) {
  int o = __builtin_amdgcn_update_dpp(__float_as_int(x), __float_as_int(x),
                                      CTRL, 0xf, 0xf, false);
  return fmaxf(x, __int_as_float(o));
}

template <int CTRL>
__device__ __forceinline__ float dpp_fadd(float x) {
  int o = __builtin_amdgcn_update_dpp(__float_as_int(x), __float_as_int(x),
                                      CTRL, 0xf, 0xf, false);
  return x + __int_as_float(o);
}

// ---------------------------------------------------------------------------
// Kernel S: 16 LANES PER CUSTOMER (k = lane&15; k>=10 idle). 4000 blocks ->
// full chip occupancy; per-lane work ~250 instr (one threefry + one gumbel).
// Argmax winner is EXACT (monotone-uint key, min-index tie-break via 15-k in
// a max-reduce; fmax/max are associative). s-sum is a fixed 16-lane tree:
// deterministic; differs from serial order by <= few ulp in slp (loss shift
// ~1e-2, threshold 7).
// ---------------------------------------------------------------------------
__global__ __launch_bounds__(256) void k_sample(
    const float* __restrict__ logits,   // (64,1001,10)
    uint32_t ks0, uint32_t ks1,
    uint8_t* __restrict__ assign,       // (64,1000)
    float* __restrict__ slp) {          // (64,1000)
  int gtid = blockIdx.x * 256 + threadIdx.x;   // 1,024,000 = 4000*256 exactly
  int cust = gtid >> 4;                 // global customer 0..63999
  int k = gtid & 15;
  int b = cust / NC, n = cust - b * NC;
  const float TINY = 1.1754943508222875e-38f;
  bool actk = (k < KC);

  float x = actk ? logits[((size_t)b * 1001 + (size_t)(n + 1)) * KC + k]
                 : -INFINITY;
  float v = -INFINITY;
  if (actk) {
    uint32_t bits = rand_bits(ks0, ks1, (uint32_t)cust * (uint32_t)KC + (uint32_t)k);
    float f = __uint_as_float((bits >> 9) | 0x3f800000u) - 1.0f;
    float u = (f > 0.0f) ? f : TINY;
    float g = -logf(-logf(u));
    v = g + x;
  }
  // monotone-uint key for float compare (v finite or -INF, never NaN)
  uint32_t uv = __float_as_uint(v);
  uint32_t key = (uv & 0x80000000u) ? ~uv : (uv | 0x80000000u);
  unsigned long long pk =
      ((unsigned long long)key << 32) | (uint32_t)(15 - k);  // ties -> min k
  float bwx = x;                         // carry winner's logit
  dpp_max_step<0xB1>(pk, bwx);
  dpp_max_step<0x4E>(pk, bwx);
  dpp_max_step<0x141>(pk, bwx);
  dpp_max_step<0x140>(pk, bwx);
  int best_k = 15 - (int)(pk & 0xFu);    // uniform within group

  float xm = x;                          // -INF on idle lanes
  xm = dpp_fmax<0xB1>(xm); xm = dpp_fmax<0x4E>(xm);
  xm = dpp_fmax<0x141>(xm); xm = dpp_fmax<0x140>(xm);

  float es = actk ? expf(x - xm) : 0.0f;
  es = dpp_fadd<0xB1>(es); es = dpp_fadd<0x4E>(es);
  es = dpp_fadd<0x141>(es); es = dpp_fadd<0x140>(es);

  if (k == 0) {
    slp[cust] = (bwx - xm) - logf(es);
    assign[cust] = (uint8_t)best_k;
  }
}

// ---------------------------------------------------------------------------
// Kernel F: r6-proven geometry — 16 blocks/instance x 256 threads
// (4 blocks/CU). Redundant prep per block (cheap); 16 NN groups per block
// (256 groups/instance >= R). Last-block finalize via device-scope atomic.
// ---------------------------------------------------------------------------
__global__ __launch_bounds__(256) void k_fused(
    const float* __restrict__ coords,    // (64,1001,2)
    const float* __restrict__ demands,   // (64,1001)
    const float* __restrict__ capacity,  // (64,)
    const uint8_t* __restrict__ assign,  // (64,1000)
    const float* __restrict__ slp,       // (64,1000)
    double* __restrict__ pdist,          // (1024,) per-block partials
    double* __restrict__ lp,             // (64,)
    int* __restrict__ counter,           // (1,) zeroed before launch
    float* __restrict__ out) {           // (2,)
  int b = blockIdx.x / WPB;
  int sb = blockIdx.x % WPB;
  int tid = threadIdx.x;
  int lane = tid & 63, wv = tid >> 6;    // 4 waves

  __shared__ float memx[NC], memy[NC], memd[NC];
  __shared__ uint16_t rs_[NC], rl_[NC];
  __shared__ uint32_t grt[MAXR];
  __shared__ int wsum[4][KC];
  __shared__ int mc[KC], mbase[KC], rc[KC], rbase[KC];
  __shared__ int rtot_s;
  __shared__ int is_last;
  __shared__ double dred[4];

  // ---- entry loads (guarded chunk of 4; NC%4==0) ----
  const float* cb = coords + (size_t)b * 1001 * 2;
  int i0 = tid * 4;
  bool valid = (i0 < NC);
  int a0 = 0xFF, a1 = 0xFF, a2 = 0xFF, a3 = 0xFF;
  float x0f = 0, y0f = 0, d0f = 0, x1f = 0, y1f = 0, d1f = 0;
  float x2f = 0, y2f = 0, d2f = 0, x3f = 0, y3f = 0, d3f = 0;
  if (valid) {
    const float* db = demands + (size_t)b * 1001;
    const float2* cb2 = reinterpret_cast<const float2*>(cb);
    uchar4 av = *(const uchar4*)(assign + (size_t)b * NC + i0);
    a0 = av.x; a1 = av.y; a2 = av.z; a3 = av.w;
    float2 c0 = cb2[i0 + 1], c1 = cb2[i0 + 2], c2 = cb2[i0 + 3], c3 = cb2[i0 + 4];
    x0f = c0.x; y0f = c0.y; d0f = db[i0 + 1];
    x1f = c1.x; y1f = c1.y; d1f = db[i0 + 2];
    x2f = c2.x; y2f = c2.y; d2f = db[i0 + 3];
    x3f = c3.x; y3f = c3.y; d3f = db[i0 + 4];
  }
  float cap = capacity[b];
  float dx0 = cb[0], dy0 = cb[1];

  // ---- lp reduction (sb==0 blocks only) ----
  {
    double lacc = 0.0;
    if (sb == 0)
      for (int n = tid; n < NC; n += 256) lacc += (double)slp[(size_t)b * NC + n];
    double t = lacc;
#pragma unroll
    for (int m = 1; m < 64; m <<= 1) t += __shfl_xor(t, m);
    if (lane == 0) dred[wv] = t;
  }
  __syncthreads();
  if (tid == 0 && sb == 0)
    lp[b] = dred[0] + dred[1] + dred[2] + dred[3];

  // ---- per-cluster wave scans ----
  int cnt[KC], excl[KC];
#pragma unroll
  for (int k = 0; k < KC; ++k)
    cnt[k] = (a0 == k) + (a1 == k) + (a2 == k) + (a3 == k);
#pragma unroll
  for (int k = 0; k < KC; ++k) {
    int x = cnt[k];
#pragma unroll
    for (int off = 1; off < 64; off <<= 1) {
      int v = __shfl_up(x, off);
      if (lane >= off) x += v;
    }
    if (lane == 63) wsum[wv][k] = x;
    excl[k] = x - cnt[k];
  }
  __syncthreads();
  if (tid == 0) {
    int s = 0;
    for (int k = 0; k < KC; ++k) {
      int t = wsum[0][k] + wsum[1][k] + wsum[2][k] + wsum[3][k];
      mc[k] = t; mbase[k] = s; s += t;
    }
  }
  __syncthreads();
#pragma unroll
  for (int k = 0; k < KC; ++k) {
    int base = mbase[k];
    for (int w = 0; w < wv; ++w) base += wsum[w][k];
    excl[k] += base;
  }

  // ---- stable scatter into member order ----
  if (valid) {
#pragma unroll
    for (int k = 0; k < KC; ++k) {
      int pos = excl[k];
      if (a0 == k) { memx[pos] = x0f; memy[pos] = y0f; memd[pos] = d0f; pos++; }
      if (a1 == k) { memx[pos] = x1f; memy[pos] = y1f; memd[pos] = d1f; pos++; }
      if (a2 == k) { memx[pos] = x2f; memy[pos] = y2f; memd[pos] = d2f; pos++; }
      if (a3 == k) { memx[pos] = x3f; memy[pos] = y3f; memd[pos] = d3f; pos++; }
    }
  }
  __syncthreads();

  // ---- capacity split per cluster (exact f32 scan semantics) ----
  if (tid < KC) {
    int base = mbase[tid], M = mc[tid];
    int r = 0, cur = 0;
    float load = 0.0f;
    bool ne = false;
    for (int j0 = 0; j0 < M; j0 += 4) {
      float dd0 = memd[base + j0];
      float dd1 = (j0 + 1 < M) ? memd[base + j0 + 1] : 0.0f;
      float dd2 = (j0 + 2 < M) ? memd[base + j0 + 2] : 0.0f;
      float dd3 = (j0 + 3 < M) ? memd[base + j0 + 3] : 0.0f;
#define SPLIT_STEP(dd, jj)                                                    \
      if (j0 + jj < M) {                                                      \
        float d = dd;                                                         \
        if (ne && (load + d > cap)) {                                         \
          rs_[base + r] = (uint16_t)cur; rl_[base + r] = (uint16_t)(j0 + jj - cur); \
          r++; cur = j0 + jj; load = d;                                       \
        } else load += d;                                                     \
        ne = true;                                                            \
      }
      SPLIT_STEP(dd0, 0) SPLIT_STEP(dd1, 1) SPLIT_STEP(dd2, 2) SPLIT_STEP(dd3, 3)
#undef SPLIT_STEP
    }
    if (ne) { rs_[base + r] = (uint16_t)cur; rl_[base + r] = (uint16_t)(M - cur); r++; }
    rc[tid] = r;
  }
  __syncthreads();
  if (tid == 0) {
    int s = 0;
    for (int k = 0; k < KC; ++k) { rbase[k] = s; s += rc[k]; }
    rtot_s = (s < MAXR) ? s : MAXR;
  }
  __syncthreads();

  // ---- compact route table into LDS ----
  if (tid < KC) {
    int k = tid, base = mbase[k];
    for (int r = 0; r < rc[k]; ++r) {
      int slot = rbase[k] + r;
      if (slot < MAXR)
        grt[slot] =
            ((uint32_t)(base + rs_[base + r]) << 16) | (uint32_t)rl_[base + r];
    }
  }
  __syncthreads();

  // ---- NN: one 16-lane group per route ----
  int lane16 = tid & 15;
  int g = sb * 16 + (tid >> 4);
  int R = rtot_s;
  double gacc = 0.0;

  for (int r = g; r < R; r += GPI) {
    uint32_t pk = grt[r];
    int start = (int)(pk >> 16);
    int L = (int)(pk & 0xFFFFu);

    float mx0 = 0, my0 = 0, mx1 = 0, my1 = 0, mx2 = 0, my2 = 0, mx3 = 0, my3 = 0;
    uint32_t vis = 0;
#define LOADC(c, MX, MY)                                                      \
    { int s = (c) * 16 + lane16;                                              \
      if (s < L) { MX = memx[start + s]; MY = memy[start + s]; }              \
      else vis |= (1u << (c)); }
    LOADC(0, mx0, my0) LOADC(1, mx1, my1) LOADC(2, mx2, my2) LOADC(3, mx3, my3)
#undef LOADC

    float px = dx0, py = dy0, racc = 0.0f;
    for (int step = 0; step < L; ++step) {
      float bd = INFINITY; int bc = -1; float bx = 0, by = 0;
#define CAND(c, MX, MY)                                                       \
      if (!(vis & (1u << (c)))) {                                             \
        float ddx = MX - px, ddy = MY - py;                                   \
        float d = sqrtf(ddx * ddx + ddy * ddy);                               \
        if (d < bd) { bd = d; bc = (c); bx = MX; by = MY; }                   \
      }
      CAND(0, mx0, my0) CAND(1, mx1, my1) CAND(2, mx2, my2) CAND(3, mx3, my3)
#undef CAND
      unsigned long long comb = (bc < 0)
          ? ~0ull
          : (((unsigned long long)__float_as_uint(bd)) << 32) |
            (unsigned)(bc * 16 + lane16);
      dpp_min_step<0xB1>(comb, bx, by);
      dpp_min_step<0x4E>(comb, bx, by);
      dpp_min_step<0x141>(comb, bx, by);
      dpp_min_step<0x140>(comb, bx, by);
      int slot = (int)(comb & 0xFFFFFFFFull);
      float best = __uint_as_float((uint32_t)(comb >> 32));
      int src16 = slot & 15, cu = slot >> 4;
      if (src16 == lane16) vis |= (1u << cu);
      px = bx; py = by;
      racc += best;                        // f32, reference scan order
    }
    float ddx = px - dx0, ddy = py - dy0;
    racc += sqrtf(ddx * ddx + ddy * ddy);  // return-to-depot leg
    gacc += (double)racc;
  }

  // ---- block partial (wave butterfly + cross-wave, deterministic) ----
  {
    double t = (lane16 == 0) ? gacc : 0.0;
#pragma unroll
    for (int m = 1; m < 64; m <<= 1) t += __shfl_xor(t, m);
    if (lane == 0) dred[wv] = t;
  }
  __syncthreads();
  if (tid == 0)
    pdist[blockIdx.x] = dred[0] + dred[1] + dred[2] + dred[3];

  // ---- last-block finalize (device-scope release/acquire, proven r7-r11) --
  if (tid == 0) {
    __threadfence();
    int old = atomicAdd(counter, 1);
    __threadfence();
    is_last = (old == (int)gridDim.x - 1);
  }
  __syncthreads();
  if (is_last) {
    __threadfence();
    if (tid < 64) {
      const double* pb = pdist + tid * WPB;
      double dd = 0.0;
      for (int j = 0; j < WPB; ++j) dd += pb[j];   // fixed order
      float df = (float)dd;
      float lf = (float)lp[tid];
      double m = (double)df;
#pragma unroll
      for (int m2 = 1; m2 < 64; m2 <<= 1) m += __shfl_xor(m, m2);
      double mean = m / 64.0;
      float meanf = (float)mean;
      double li = ((double)df - (double)meanf) * (double)lf;
#pragma unroll
      for (int m2 = 1; m2 < 64; m2 <<= 1) li += __shfl_xor(li, m2);
      if (tid == 0) {
        out[0] = (float)(li / 64.0);
        out[1] = meanf;
      }
    }
  }
}

extern "C" void kernel_launch(void* const* d_in, const int* in_sizes, int n_in,
                              void* d_out, int out_size, void* d_ws, size_t ws_size,
                              hipStream_t stream) {
  const float* logits   = (const float*)d_in[0];  // (64,1001,10)
  const float* coords   = (const float*)d_in[1];  // (64,1001,2)
  const float* demands  = (const float*)d_in[2];  // (64,1001)
  const float* capacity = (const float*)d_in[3];  // (64,)

  uint8_t* ws = (uint8_t*)d_ws;
  double*  pdist   = (double*)(ws);            // 8192 B (1024 doubles)
  double*  lp      = (double*)(ws + 8192);     // 512 B
  int*     counter = (int*)(ws + 8704);        // 4 B (zeroed every call)
  uint8_t* assign  = (uint8_t*)(ws + 9216);    // 64000 B
  float*   slp     = (float*)(ws + 73216);     // 256000 B

  uint32_t ks0, ks1;
  threefry2x32(0u, 42u, 0u, 0u, &ks0, &ks1);   // fold_in(key(42), 0)

  hipMemsetAsync(counter, 0, sizeof(int), stream);
  k_sample<<<dim3(BB * NC * 16 / 256), dim3(256), 0, stream>>>(
      logits, ks0, ks1, assign, slp);
  k_fused<<<dim3(BB * WPB), dim3(256), 0, stream>>>(
      coords, demands, capacity, assign, slp,
      pdist, lp, counter, (float*)d_out);
}

// Round 13
// 41.100 us; speedup vs baseline: 1.5975x; 1.5975x over previous
//
#include <hip/hip_runtime.h>
#include <stdint.h>

#define BB 64
#define NC 1000       // customers per instance
#define KC 10         // clusters
#define MAXR 512      // routes per instance upper bound (realistic max ~140)
#define WPB 16        // blocks per instance in fused kernel
#define GPI (WPB * 16)  // 16-lane NN groups per instance = 256

__host__ __device__ inline void threefry2x32(uint32_t k0, uint32_t k1,
                                             uint32_t x0, uint32_t x1,
                                             uint32_t* o0, uint32_t* o1) {
  uint32_t k2 = k0 ^ k1 ^ 0x1BD11BDAu;
  x0 += k0; x1 += k1;
#define TF_R(R) { x0 += x1; x1 = (x1 << (R)) | (x1 >> (32 - (R))); x1 ^= x0; }
  TF_R(13) TF_R(15) TF_R(26) TF_R(6)
  x0 += k1; x1 += k2 + 1u;
  TF_R(17) TF_R(29) TF_R(16) TF_R(24)
  x0 += k2; x1 += k0 + 2u;
  TF_R(13) TF_R(15) TF_R(26) TF_R(6)
  x0 += k0; x1 += k1 + 3u;
  TF_R(17) TF_R(29) TF_R(16) TF_R(24)
  x0 += k1; x1 += k2 + 4u;
  TF_R(13) TF_R(15) TF_R(26) TF_R(6)
  x0 += k2; x1 += k0 + 5u;
#undef TF_R
  *o0 = x0; *o1 = x1;
}

__device__ inline uint32_t rand_bits(uint32_t ks0, uint32_t ks1, uint32_t p) {
  uint32_t a, b; threefry2x32(ks0, ks1, 0u, p, &a, &b); return b;
}

// ---- 16-lane DPP helpers (each 16-lane group = one DPP row; call sites are
// ---- convergent -> all source lanes active). CTRLs: 0xB1 lane^1, 0x4E lane^2,
// ---- 0x141 half-mirror (xor4 effective), 0x140 mirror (xor8 effective).
template <int CTRL>
__device__ __forceinline__ void dpp_min_step(unsigned long long& comb,
                                             float& x, float& y) {
  int lo = (int)(uint32_t)comb;
  int hi = (int)(uint32_t)(comb >> 32);
  int olo = __builtin_amdgcn_update_dpp(lo, lo, CTRL, 0xf, 0xf, false);
  int ohi = __builtin_amdgcn_update_dpp(hi, hi, CTRL, 0xf, 0xf, false);
  int oxi = __builtin_amdgcn_update_dpp(__float_as_int(x), __float_as_int(x),
                                        CTRL, 0xf, 0xf, false);
  int oyi = __builtin_amdgcn_update_dpp(__float_as_int(y), __float_as_int(y),
                                        CTRL, 0xf, 0xf, false);
  unsigned long long o =
      ((unsigned long long)(uint32_t)ohi << 32) | (uint32_t)olo;
  if (o < comb) { comb = o; x = __int_as_float(oxi); y = __int_as_float(oyi); }
}

template <int CTRL>
__device__ __forceinline__ void dpp_max_step(unsigned long long& pk, float& x) {
  int lo = (int)(uint32_t)pk;
  int hi = (int)(uint32_t)(pk >> 32);
  int olo = __builtin_amdgcn_update_dpp(lo, lo, CTRL, 0xf, 0xf, false);
  int ohi = __builtin_amdgcn_update_dpp(hi, hi, CTRL, 0xf, 0xf, false);
  int oxi = __builtin_amdgcn_update_dpp(__float_as_int(x), __float_as_int(x),
                                        CTRL, 0xf, 0xf, false);
  unsigned long long o =
      ((unsigned long long)(uint32_t)ohi << 32) | (uint32_t)olo;
  if (o > pk) { pk = o; x = __int_as_float(oxi); }
}

template <int CTRL>
__device__ __forceinline__ float dpp_fmax(float x) {
  int o = __builtin_amdgcn_update_dpp(__float_as_int(x), __float_as_int(x),
                                      CTRL, 0xf, 0xf, false);
  return fmaxf(x, __int_as_float(o));
}

template <int CTRL>
__device__ __forceinline__ float dpp_fadd(float x) {
  int o = __builtin_amdgcn_update_dpp(__float_as_int(x), __float_as_int(x),
                                      CTRL, 0xf, 0xf, false);
  return x + __int_as_float(o);
}

// ---------------------------------------------------------------------------
// Kernel S: 16 LANES PER CUSTOMER (k = lane&15; k>=10 idle). 4000 blocks ->
// full chip occupancy; per-lane work ~250 instr. Passed r12, absmax 2.5.
// ---------------------------------------------------------------------------
__global__ __launch_bounds__(256) void k_sample(
    const float* __restrict__ logits,   // (64,1001,10)
    uint32_t ks0, uint32_t ks1,
    uint8_t* __restrict__ assign,       // (64,1000)
    float* __restrict__ slp) {          // (64,1000)
  int gtid = blockIdx.x * 256 + threadIdx.x;   // 1,024,000 = 4000*256 exactly
  int cust = gtid >> 4;                 // global customer 0..63999
  int k = gtid & 15;
  int b = cust / NC, n = cust - b * NC;
  const float TINY = 1.1754943508222875e-38f;
  bool actk = (k < KC);

  float x = actk ? logits[((size_t)b * 1001 + (size_t)(n + 1)) * KC + k]
                 : -INFINITY;
  float v = -INFINITY;
  if (actk) {
    uint32_t bits = rand_bits(ks0, ks1, (uint32_t)cust * (uint32_t)KC + (uint32_t)k);
    float f = __uint_as_float((bits >> 9) | 0x3f800000u) - 1.0f;
    float u = (f > 0.0f) ? f : TINY;
    float g = -logf(-logf(u));
    v = g + x;
  }
  // monotone-uint key for float compare (v finite or -INF, never NaN)
  uint32_t uv = __float_as_uint(v);
  uint32_t key = (uv & 0x80000000u) ? ~uv : (uv | 0x80000000u);
  unsigned long long pk =
      ((unsigned long long)key << 32) | (uint32_t)(15 - k);  // ties -> min k
  float bwx = x;                         // carry winner's logit
  dpp_max_step<0xB1>(pk, bwx);
  dpp_max_step<0x4E>(pk, bwx);
  dpp_max_step<0x141>(pk, bwx);
  dpp_max_step<0x140>(pk, bwx);
  int best_k = 15 - (int)(pk & 0xFu);    // uniform within group

  float xm = x;                          // -INF on idle lanes
  xm = dpp_fmax<0xB1>(xm); xm = dpp_fmax<0x4E>(xm);
  xm = dpp_fmax<0x141>(xm); xm = dpp_fmax<0x140>(xm);

  float es = actk ? expf(x - xm) : 0.0f;
  es = dpp_fadd<0xB1>(es); es = dpp_fadd<0x4E>(es);
  es = dpp_fadd<0x141>(es); es = dpp_fadd<0x140>(es);

  if (k == 0) {
    slp[cust] = (bwx - xm) - logf(es);
    assign[cust] = (uint8_t)best_k;
  }
}

// ---------------------------------------------------------------------------
// Kernel F: 16 blocks/instance x 256 threads. NO device-scope fences/atomics
// (r12's last-block finalize cost ~40 us in fences at 1024 blocks).
// Each block writes its pdist partial; sb==0 also reduces lp.
// ---------------------------------------------------------------------------
__global__ __launch_bounds__(256) void k_fused(
    const float* __restrict__ coords,    // (64,1001,2)
    const float* __restrict__ demands,   // (64,1001)
    const float* __restrict__ capacity,  // (64,)
    const uint8_t* __restrict__ assign,  // (64,1000)
    const float* __restrict__ slp,       // (64,1000)
    double* __restrict__ pdist,          // (1024,) per-block partials
    double* __restrict__ lp) {           // (64,)
  int b = blockIdx.x / WPB;
  int sb = blockIdx.x % WPB;
  int tid = threadIdx.x;
  int lane = tid & 63, wv = tid >> 6;    // 4 waves

  __shared__ float memx[NC], memy[NC], memd[NC];
  __shared__ uint16_t rs_[NC], rl_[NC];
  __shared__ uint32_t grt[MAXR];
  __shared__ int wsum[4][KC];
  __shared__ int mc[KC], mbase[KC], rc[KC], rbase[KC];
  __shared__ int rtot_s;
  __shared__ double dred[4];

  // ---- entry loads (guarded chunk of 4; NC%4==0) ----
  const float* cb = coords + (size_t)b * 1001 * 2;
  int i0 = tid * 4;
  bool valid = (i0 < NC);
  int a0 = 0xFF, a1 = 0xFF, a2 = 0xFF, a3 = 0xFF;
  float x0f = 0, y0f = 0, d0f = 0, x1f = 0, y1f = 0, d1f = 0;
  float x2f = 0, y2f = 0, d2f = 0, x3f = 0, y3f = 0, d3f = 0;
  if (valid) {
    const float* db = demands + (size_t)b * 1001;
    const float2* cb2 = reinterpret_cast<const float2*>(cb);
    uchar4 av = *(const uchar4*)(assign + (size_t)b * NC + i0);
    a0 = av.x; a1 = av.y; a2 = av.z; a3 = av.w;
    float2 c0 = cb2[i0 + 1], c1 = cb2[i0 + 2], c2 = cb2[i0 + 3], c3 = cb2[i0 + 4];
    x0f = c0.x; y0f = c0.y; d0f = db[i0 + 1];
    x1f = c1.x; y1f = c1.y; d1f = db[i0 + 2];
    x2f = c2.x; y2f = c2.y; d2f = db[i0 + 3];
    x3f = c3.x; y3f = c3.y; d3f = db[i0 + 4];
  }
  float cap = capacity[b];
  float dx0 = cb[0], dy0 = cb[1];

  // ---- lp reduction (sb==0 blocks only) ----
  {
    double lacc = 0.0;
    if (sb == 0)
      for (int n = tid; n < NC; n += 256) lacc += (double)slp[(size_t)b * NC + n];
    double t = lacc;
#pragma unroll
    for (int m = 1; m < 64; m <<= 1) t += __shfl_xor(t, m);
    if (lane == 0) dred[wv] = t;
  }
  __syncthreads();
  if (tid == 0 && sb == 0)
    lp[b] = dred[0] + dred[1] + dred[2] + dred[3];

  // ---- per-cluster wave scans ----
  int cnt[KC], excl[KC];
#pragma unroll
  for (int k = 0; k < KC; ++k)
    cnt[k] = (a0 == k) + (a1 == k) + (a2 == k) + (a3 == k);
#pragma unroll
  for (int k = 0; k < KC; ++k) {
    int x = cnt[k];
#pragma unroll
    for (int off = 1; off < 64; off <<= 1) {
      int v = __shfl_up(x, off);
      if (lane >= off) x += v;
    }
    if (lane == 63) wsum[wv][k] = x;
    excl[k] = x - cnt[k];
  }
  __syncthreads();
  if (tid == 0) {
    int s = 0;
    for (int k = 0; k < KC; ++k) {
      int t = wsum[0][k] + wsum[1][k] + wsum[2][k] + wsum[3][k];
      mc[k] = t; mbase[k] = s; s += t;
    }
  }
  __syncthreads();
#pragma unroll
  for (int k = 0; k < KC; ++k) {
    int base = mbase[k];
    for (int w = 0; w < wv; ++w) base += wsum[w][k];
    excl[k] += base;
  }

  // ---- stable scatter into member order ----
  if (valid) {
#pragma unroll
    for (int k = 0; k < KC; ++k) {
      int pos = excl[k];
      if (a0 == k) { memx[pos] = x0f; memy[pos] = y0f; memd[pos] = d0f; pos++; }
      if (a1 == k) { memx[pos] = x1f; memy[pos] = y1f; memd[pos] = d1f; pos++; }
      if (a2 == k) { memx[pos] = x2f; memy[pos] = y2f; memd[pos] = d2f; pos++; }
      if (a3 == k) { memx[pos] = x3f; memy[pos] = y3f; memd[pos] = d3f; pos++; }
    }
  }
  __syncthreads();

  // ---- capacity split per cluster (exact f32 scan semantics) ----
  if (tid < KC) {
    int base = mbase[tid], M = mc[tid];
    int r = 0, cur = 0;
    float load = 0.0f;
    bool ne = false;
    for (int j0 = 0; j0 < M; j0 += 4) {
      float dd0 = memd[base + j0];
      float dd1 = (j0 + 1 < M) ? memd[base + j0 + 1] : 0.0f;
      float dd2 = (j0 + 2 < M) ? memd[base + j0 + 2] : 0.0f;
      float dd3 = (j0 + 3 < M) ? memd[base + j0 + 3] : 0.0f;
#define SPLIT_STEP(dd, jj)                                                    \
      if (j0 + jj < M) {                                                      \
        float d = dd;                                                         \
        if (ne && (load + d > cap)) {                                         \
          rs_[base + r] = (uint16_t)cur; rl_[base + r] = (uint16_t)(j0 + jj - cur); \
          r++; cur = j0 + jj; load = d;                                       \
        } else load += d;                                                     \
        ne = true;                                                            \
      }
      SPLIT_STEP(dd0, 0) SPLIT_STEP(dd1, 1) SPLIT_STEP(dd2, 2) SPLIT_STEP(dd3, 3)
#undef SPLIT_STEP
    }
    if (ne) { rs_[base + r] = (uint16_t)cur; rl_[base + r] = (uint16_t)(M - cur); r++; }
    rc[tid] = r;
  }
  __syncthreads();
  if (tid == 0) {
    int s = 0;
    for (int k = 0; k < KC; ++k) { rbase[k] = s; s += rc[k]; }
    rtot_s = (s < MAXR) ? s : MAXR;
  }
  __syncthreads();

  // ---- compact route table into LDS ----
  if (tid < KC) {
    int k = tid, base = mbase[k];
    for (int r = 0; r < rc[k]; ++r) {
      int slot = rbase[k] + r;
      if (slot < MAXR)
        grt[slot] =
            ((uint32_t)(base + rs_[base + r]) << 16) | (uint32_t)rl_[base + r];
    }
  }
  __syncthreads();

  // ---- NN: one 16-lane group per route ----
  int lane16 = tid & 15;
  int g = sb * 16 + (tid >> 4);
  int R = rtot_s;
  double gacc = 0.0;

  for (int r = g; r < R; r += GPI) {
    uint32_t pk = grt[r];
    int start = (int)(pk >> 16);
    int L = (int)(pk & 0xFFFFu);

    float mx0 = 0, my0 = 0, mx1 = 0, my1 = 0, mx2 = 0, my2 = 0, mx3 = 0, my3 = 0;
    uint32_t vis = 0;
#define LOADC(c, MX, MY)                                                      \
    { int s = (c) * 16 + lane16;                                              \
      if (s < L) { MX = memx[start + s]; MY = memy[start + s]; }              \
      else vis |= (1u << (c)); }
    LOADC(0, mx0, my0) LOADC(1, mx1, my1) LOADC(2, mx2, my2) LOADC(3, mx3, my3)
#undef LOADC

    float px = dx0, py = dy0, racc = 0.0f;
    for (int step = 0; step < L; ++step) {
      float bd = INFINITY; int bc = -1; float bx = 0, by = 0;
#define CAND(c, MX, MY)                                                       \
      if (!(vis & (1u << (c)))) {                                             \
        float ddx = MX - px, ddy = MY - py;                                   \
        float d = sqrtf(ddx * ddx + ddy * ddy);                               \
        if (d < bd) { bd = d; bc = (c); bx = MX; by = MY; }                   \
      }
      CAND(0, mx0, my0) CAND(1, mx1, my1) CAND(2, mx2, my2) CAND(3, mx3, my3)
#undef CAND
      unsigned long long comb = (bc < 0)
          ? ~0ull
          : (((unsigned long long)__float_as_uint(bd)) << 32) |
            (unsigned)(bc * 16 + lane16);
      dpp_min_step<0xB1>(comb, bx, by);
      dpp_min_step<0x4E>(comb, bx, by);
      dpp_min_step<0x141>(comb, bx, by);
      dpp_min_step<0x140>(comb, bx, by);
      int slot = (int)(comb & 0xFFFFFFFFull);
      float best = __uint_as_float((uint32_t)(comb >> 32));
      int src16 = slot & 15, cu = slot >> 4;
      if (src16 == lane16) vis |= (1u << cu);
      px = bx; py = by;
      racc += best;                        // f32, reference scan order
    }
    float ddx = px - dx0, ddy = py - dy0;
    racc += sqrtf(ddx * ddx + ddy * ddy);  // return-to-depot leg
    gacc += (double)racc;
  }

  // ---- block partial (wave butterfly + cross-wave, deterministic) ----
  {
    double t = (lane16 == 0) ? gacc : 0.0;
#pragma unroll
    for (int m = 1; m < 64; m <<= 1) t += __shfl_xor(t, m);
    if (lane == 0) dred[wv] = t;
  }
  __syncthreads();
  if (tid == 0)
    pdist[blockIdx.x] = dred[0] + dred[1] + dred[2] + dred[3];
}

// ---------------------------------------------------------------------------
// Kernel C: loss finalize. 1 block x 64 threads; thread i = instance i.
// Same summation order as r12's last-block finalize (passed, absmax 2.5).
// ---------------------------------------------------------------------------
__global__ __launch_bounds__(64) void k_final(
    const double* __restrict__ pdist,    // (1024,)
    const double* __restrict__ lp,       // (64,)
    float* __restrict__ out) {           // (2,)
  int tid = threadIdx.x;
  const double* pb = pdist + tid * WPB;
  double dd = 0.0;
  for (int j = 0; j < WPB; ++j) dd += pb[j];     // fixed order
  float df = (float)dd;
  float lf = (float)lp[tid];
  double m = (double)df;
#pragma unroll
  for (int m2 = 1; m2 < 64; m2 <<= 1) m += __shfl_xor(m, m2);
  double mean = m / 64.0;
  float meanf = (float)mean;
  double li = ((double)df - (double)meanf) * (double)lf;
#pragma unroll
  for (int m2 = 1; m2 < 64; m2 <<= 1) li += __shfl_xor(li, m2);
  if (tid == 0) {
    out[0] = (float)(li / 64.0);
    out[1] = meanf;
  }
}

extern "C" void kernel_launch(void* const* d_in, const int* in_sizes, int n_in,
                              void* d_out, int out_size, void* d_ws, size_t ws_size,
                              hipStream_t stream) {
  const float* logits   = (const float*)d_in[0];  // (64,1001,10)
  const float* coords   = (const float*)d_in[1];  // (64,1001,2)
  const float* demands  = (const float*)d_in[2];  // (64,1001)
  const float* capacity = (const float*)d_in[3];  // (64,)

  uint8_t* ws = (uint8_t*)d_ws;
  double*  pdist  = (double*)(ws);            // 8192 B (1024 doubles)
  double*  lp     = (double*)(ws + 8192);     // 512 B
  uint8_t* assign = (uint8_t*)(ws + 9216);    // 64000 B
  float*   slp    = (float*)(ws + 73216);     // 256000 B

  uint32_t ks0, ks1;
  threefry2x32(0u, 42u, 0u, 0u, &ks0, &ks1);   // fold_in(key(42), 0)

  k_sample<<<dim3(BB * NC * 16 / 256), dim3(256), 0, stream>>>(
      logits, ks0, ks1, assign, slp);
  k_fused<<<dim3(BB * WPB), dim3(256), 0, stream>>>(
      coords, demands, capacity, assign, slp, pdist, lp);
  k_final<<<dim3(1), dim3(64), 0, stream>>>(pdist, lp, (float*)d_out);
}

// Round 14
// 40.159 us; speedup vs baseline: 1.6350x; 1.0234x over previous
//
#include <hip/hip_runtime.h>
#include <stdint.h>

#define BB 64
#define NC 1000       // customers per instance
#define KC 10         // clusters
#define MAXR 512      // routes per instance upper bound (realistic max ~140)
#define WPB 16        // blocks per instance in fused kernel
#define GPI (WPB * 16)  // 16-lane NN groups per instance = 256
#define DPAD 196      // padded per-cluster demand stride (16B-aligned, 9.8 sigma)

__host__ __device__ inline void threefry2x32(uint32_t k0, uint32_t k1,
                                             uint32_t x0, uint32_t x1,
                                             uint32_t* o0, uint32_t* o1) {
  uint32_t k2 = k0 ^ k1 ^ 0x1BD11BDAu;
  x0 += k0; x1 += k1;
#define TF_R(R) { x0 += x1; x1 = (x1 << (R)) | (x1 >> (32 - (R))); x1 ^= x0; }
  TF_R(13) TF_R(15) TF_R(26) TF_R(6)
  x0 += k1; x1 += k2 + 1u;
  TF_R(17) TF_R(29) TF_R(16) TF_R(24)
  x0 += k2; x1 += k0 + 2u;
  TF_R(13) TF_R(15) TF_R(26) TF_R(6)
  x0 += k0; x1 += k1 + 3u;
  TF_R(17) TF_R(29) TF_R(16) TF_R(24)
  x0 += k1; x1 += k2 + 4u;
  TF_R(13) TF_R(15) TF_R(26) TF_R(6)
  x0 += k2; x1 += k0 + 5u;
#undef TF_R
  *o0 = x0; *o1 = x1;
}

__device__ inline uint32_t rand_bits(uint32_t ks0, uint32_t ks1, uint32_t p) {
  uint32_t a, b; threefry2x32(ks0, ks1, 0u, p, &a, &b); return b;
}

// ---- 16-lane DPP helpers (16-lane group = one DPP row; convergent calls) ----
template <int CTRL>
__device__ __forceinline__ void dpp_min_step(unsigned long long& comb,
                                             float& x, float& y) {
  int lo = (int)(uint32_t)comb;
  int hi = (int)(uint32_t)(comb >> 32);
  int olo = __builtin_amdgcn_update_dpp(lo, lo, CTRL, 0xf, 0xf, false);
  int ohi = __builtin_amdgcn_update_dpp(hi, hi, CTRL, 0xf, 0xf, false);
  int oxi = __builtin_amdgcn_update_dpp(__float_as_int(x), __float_as_int(x),
                                        CTRL, 0xf, 0xf, false);
  int oyi = __builtin_amdgcn_update_dpp(__float_as_int(y), __float_as_int(y),
                                        CTRL, 0xf, 0xf, false);
  unsigned long long o =
      ((unsigned long long)(uint32_t)ohi << 32) | (uint32_t)olo;
  if (o < comb) { comb = o; x = __int_as_float(oxi); y = __int_as_float(oyi); }
}

template <int CTRL>
__device__ __forceinline__ void dpp_max_step(unsigned long long& pk, float& x) {
  int lo = (int)(uint32_t)pk;
  int hi = (int)(uint32_t)(pk >> 32);
  int olo = __builtin_amdgcn_update_dpp(lo, lo, CTRL, 0xf, 0xf, false);
  int ohi = __builtin_amdgcn_update_dpp(hi, hi, CTRL, 0xf, 0xf, false);
  int oxi = __builtin_amdgcn_update_dpp(__float_as_int(x), __float_as_int(x),
                                        CTRL, 0xf, 0xf, false);
  unsigned long long o =
      ((unsigned long long)(uint32_t)ohi << 32) | (uint32_t)olo;
  if (o > pk) { pk = o; x = __int_as_float(oxi); }
}

template <int CTRL>
__device__ __forceinline__ float dpp_fmax(float x) {
  int o = __builtin_amdgcn_update_dpp(__float_as_int(x), __float_as_int(x),
                                      CTRL, 0xf, 0xf, false);
  return fmaxf(x, __int_as_float(o));
}

template <int CTRL>
__device__ __forceinline__ float dpp_fadd(float x) {
  int o = __builtin_amdgcn_update_dpp(__float_as_int(x), __float_as_int(x),
                                      CTRL, 0xf, 0xf, false);
  return x + __int_as_float(o);
}

// ---------------------------------------------------------------------------
// Kernel S: 16 lanes per customer (passed r12/r13, absmax 2.5). Unchanged.
// ---------------------------------------------------------------------------
__global__ __launch_bounds__(256) void k_sample(
    const float* __restrict__ logits,   // (64,1001,10)
    uint32_t ks0, uint32_t ks1,
    uint8_t* __restrict__ assign,       // (64,1000)
    float* __restrict__ slp) {          // (64,1000)
  int gtid = blockIdx.x * 256 + threadIdx.x;   // 1,024,000 = 4000*256
  int cust = gtid >> 4;
  int k = gtid & 15;
  int b = cust / NC, n = cust - b * NC;
  const float TINY = 1.1754943508222875e-38f;
  bool actk = (k < KC);

  float x = actk ? logits[((size_t)b * 1001 + (size_t)(n + 1)) * KC + k]
                 : -INFINITY;
  float v = -INFINITY;
  if (actk) {
    uint32_t bits = rand_bits(ks0, ks1, (uint32_t)cust * (uint32_t)KC + (uint32_t)k);
    float f = __uint_as_float((bits >> 9) | 0x3f800000u) - 1.0f;
    float u = (f > 0.0f) ? f : TINY;
    float g = -logf(-logf(u));
    v = g + x;
  }
  uint32_t uv = __float_as_uint(v);
  uint32_t key = (uv & 0x80000000u) ? ~uv : (uv | 0x80000000u);
  unsigned long long pk =
      ((unsigned long long)key << 32) | (uint32_t)(15 - k);  // ties -> min k
  float bwx = x;
  dpp_max_step<0xB1>(pk, bwx);
  dpp_max_step<0x4E>(pk, bwx);
  dpp_max_step<0x141>(pk, bwx);
  dpp_max_step<0x140>(pk, bwx);
  int best_k = 15 - (int)(pk & 0xFu);

  float xm = x;
  xm = dpp_fmax<0xB1>(xm); xm = dpp_fmax<0x4E>(xm);
  xm = dpp_fmax<0x141>(xm); xm = dpp_fmax<0x140>(xm);

  float es = actk ? expf(x - xm) : 0.0f;
  es = dpp_fadd<0xB1>(es); es = dpp_fadd<0x4E>(es);
  es = dpp_fadd<0x141>(es); es = dpp_fadd<0x140>(es);

  if (k == 0) {
    slp[cust] = (bwx - xm) - logf(es);
    assign[cust] = (uint8_t)best_k;
  }
}

// ---------------------------------------------------------------------------
// Kernel F: prep + NN, no fences. Split walk rewritten branch-free:
// demands scattered into zero-padded dem_pad[k][rank]; float4 reads with
// one-iteration prefetch; padding zeros provably never split (load <= cap
// inductively, so load+0 > cap is false) -> bit-identical routes.
// ---------------------------------------------------------------------------
__global__ __launch_bounds__(256) void k_fused(
    const float* __restrict__ coords,    // (64,1001,2)
    const float* __restrict__ demands,   // (64,1001)
    const float* __restrict__ capacity,  // (64,)
    const uint8_t* __restrict__ assign,  // (64,1000)
    const float* __restrict__ slp,       // (64,1000)
    double* __restrict__ pdist,          // (1024,) per-block partials
    double* __restrict__ lp) {           // (64,)
  int b = blockIdx.x / WPB;
  int sb = blockIdx.x % WPB;
  int tid = threadIdx.x;
  int lane = tid & 63, wv = tid >> 6;    // 4 waves

  __shared__ float memx[NC], memy[NC];
  __shared__ float dem_pad[KC][DPAD];    // zero-padded demands by (cluster,rank)
  __shared__ uint16_t rs_[NC], rl_[NC];
  __shared__ uint32_t grt[MAXR];
  __shared__ int wsum[4][KC];
  __shared__ int mc[KC], mbase[KC], rc[KC], rbase[KC];
  __shared__ int rtot_s;
  __shared__ double dred[4];

  // ---- zero-init dem_pad (padding correctness depends on this) ----
  {
    float* dp = &dem_pad[0][0];
    for (int i = tid; i < KC * DPAD; i += 256) dp[i] = 0.0f;
  }

  // ---- entry loads (guarded chunk of 4; NC%4==0) ----
  const float* cb = coords + (size_t)b * 1001 * 2;
  int i0 = tid * 4;
  bool valid = (i0 < NC);
  int a0 = 0xFF, a1 = 0xFF, a2 = 0xFF, a3 = 0xFF;
  float x0f = 0, y0f = 0, d0f = 0, x1f = 0, y1f = 0, d1f = 0;
  float x2f = 0, y2f = 0, d2f = 0, x3f = 0, y3f = 0, d3f = 0;
  if (valid) {
    const float* db = demands + (size_t)b * 1001;
    const float2* cb2 = reinterpret_cast<const float2*>(cb);
    uchar4 av = *(const uchar4*)(assign + (size_t)b * NC + i0);
    a0 = av.x; a1 = av.y; a2 = av.z; a3 = av.w;
    float2 c0 = cb2[i0 + 1], c1 = cb2[i0 + 2], c2 = cb2[i0 + 3], c3 = cb2[i0 + 4];
    x0f = c0.x; y0f = c0.y; d0f = db[i0 + 1];
    x1f = c1.x; y1f = c1.y; d1f = db[i0 + 2];
    x2f = c2.x; y2f = c2.y; d2f = db[i0 + 3];
    x3f = c3.x; y3f = c3.y; d3f = db[i0 + 4];
  }
  float cap = capacity[b];
  float dx0 = cb[0], dy0 = cb[1];

  // ---- lp reduction (sb==0 blocks only; order as r13 -> bit-identical) ----
  {
    double lacc = 0.0;
    if (sb == 0)
      for (int n = tid; n < NC; n += 256) lacc += (double)slp[(size_t)b * NC + n];
    double t = lacc;
#pragma unroll
    for (int m = 1; m < 64; m <<= 1) t += __shfl_xor(t, m);
    if (lane == 0) dred[wv] = t;
  }
  __syncthreads();
  if (tid == 0 && sb == 0)
    lp[b] = dred[0] + dred[1] + dred[2] + dred[3];

  // ---- per-cluster wave scans ----
  int cnt[KC], excl[KC];
#pragma unroll
  for (int k = 0; k < KC; ++k)
    cnt[k] = (a0 == k) + (a1 == k) + (a2 == k) + (a3 == k);
#pragma unroll
  for (int k = 0; k < KC; ++k) {
    int x = cnt[k];
#pragma unroll
    for (int off = 1; off < 64; off <<= 1) {
      int v = __shfl_up(x, off);
      if (lane >= off) x += v;
    }
    if (lane == 63) wsum[wv][k] = x;
    excl[k] = x - cnt[k];
  }
  __syncthreads();
  if (tid == 0) {
    int s = 0;
    for (int k = 0; k < KC; ++k) {
      int t = wsum[0][k] + wsum[1][k] + wsum[2][k] + wsum[3][k];
      mc[k] = t; mbase[k] = s; s += t;
    }
  }
  __syncthreads();
#pragma unroll
  for (int k = 0; k < KC; ++k) {
    int base = mbase[k];
    for (int w = 0; w < wv; ++w) base += wsum[w][k];
    excl[k] += base;
  }

  // ---- stable scatter: coords to member order, demands to (cluster,rank) ---
  if (valid) {
#pragma unroll
    for (int k = 0; k < KC; ++k) {
      int pos = excl[k];
#define SCAT(A, X, Y, D)                                                      \
      if (A == k) {                                                           \
        memx[pos] = X; memy[pos] = Y;                                         \
        int rk = pos - mbase[k];                                              \
        if (rk < DPAD) dem_pad[k][rk] = D;                                    \
        pos++;                                                                \
      }
      SCAT(a0, x0f, y0f, d0f) SCAT(a1, x1f, y1f, d1f)
      SCAT(a2, x2f, y2f, d2f) SCAT(a3, x3f, y3f, d3f)
#undef SCAT
    }
  }
  __syncthreads();

  // ---- capacity split: branch-free float4 walk with prefetch ----
  if (tid < KC) {
    int M = mc[tid];
    int r = 0;
    if (M > 0) {
      const float4* dp4 = reinterpret_cast<const float4*>(&dem_pad[tid][0]);
      int base = mbase[tid];
      int trips = (M + 3) >> 2;          // trips*4+3 <= 195 for M <= 192
      float load = 0.0f;
      int cur = 0;
      float4 cv = dp4[0];
      for (int t = 0; t < trips; ++t) {
        float4 nv = dp4[t + 1];          // prefetch next 4 (padded, in-bounds)
#define SPLIT_E(DV, E)                                                        \
        {                                                                     \
          int j = t * 4 + E;                                                  \
          float d = DV;                                                       \
          if (j == 0) load = d;                                               \
          else if (load + d > cap) {                                          \
            rs_[base + r] = (uint16_t)cur;                                    \
            rl_[base + r] = (uint16_t)(j - cur);                              \
            r++; cur = j; load = d;                                           \
          } else load += d;              /* padding d=0: load<=cap -> no-op */\
        }
        SPLIT_E(cv.x, 0) SPLIT_E(cv.y, 1) SPLIT_E(cv.z, 2) SPLIT_E(cv.w, 3)
#undef SPLIT_E
        cv = nv;
      }
      rs_[base + r] = (uint16_t)cur;
      rl_[base + r] = (uint16_t)(M - cur);
      r++;
    }
    rc[tid] = r;
  }
  __syncthreads();
  if (tid == 0) {
    int s = 0;
    for (int k = 0; k < KC; ++k) { rbase[k] = s; s += rc[k]; }
    rtot_s = (s < MAXR) ? s : MAXR;
  }
  __syncthreads();

  // ---- compact route table into LDS ----
  if (tid < KC) {
    int k = tid, base = mbase[k];
    for (int r = 0; r < rc[k]; ++r) {
      int slot = rbase[k] + r;
      if (slot < MAXR)
        grt[slot] =
            ((uint32_t)(base + rs_[base + r]) << 16) | (uint32_t)rl_[base + r];
    }
  }
  __syncthreads();

  // ---- NN: one 16-lane group per route ----
  int lane16 = tid & 15;
  int g = sb * 16 + (tid >> 4);
  int R = rtot_s;
  double gacc = 0.0;

  for (int r = g; r < R; r += GPI) {
    uint32_t pk = grt[r];
    int start = (int)(pk >> 16);
    int L = (int)(pk & 0xFFFFu);

    float mx0 = 0, my0 = 0, mx1 = 0, my1 = 0, mx2 = 0, my2 = 0, mx3 = 0, my3 = 0;
    uint32_t vis = 0;
#define LOADC(c, MX, MY)                                                      \
    { int s = (c) * 16 + lane16;                                              \
      if (s < L) { MX = memx[start + s]; MY = memy[start + s]; }              \
      else vis |= (1u << (c)); }
    LOADC(0, mx0, my0) LOADC(1, mx1, my1) LOADC(2, mx2, my2) LOADC(3, mx3, my3)
#undef LOADC

    float px = dx0, py = dy0, racc = 0.0f;
    for (int step = 0; step < L; ++step) {
      float bd = INFINITY; int bc = -1; float bx = 0, by = 0;
#define CAND(c, MX, MY)                                                       \
      if (!(vis & (1u << (c)))) {                                             \
        float ddx = MX - px, ddy = MY - py;                                   \
        float d = sqrtf(ddx * ddx + ddy * ddy);                               \
        if (d < bd) { bd = d; bc = (c); bx = MX; by = MY; }                   \
      }
      CAND(0, mx0, my0) CAND(1, mx1, my1) CAND(2, mx2, my2) CAND(3, mx3, my3)
#undef CAND
      unsigned long long comb = (bc < 0)
          ? ~0ull
          : (((unsigned long long)__float_as_uint(bd)) << 32) |
            (unsigned)(bc * 16 + lane16);
      dpp_min_step<0xB1>(comb, bx, by);
      dpp_min_step<0x4E>(comb, bx, by);
      dpp_min_step<0x141>(comb, bx, by);
      dpp_min_step<0x140>(comb, bx, by);
      int slot = (int)(comb & 0xFFFFFFFFull);
      float best = __uint_as_float((uint32_t)(comb >> 32));
      int src16 = slot & 15, cu = slot >> 4;
      if (src16 == lane16) vis |= (1u << cu);
      px = bx; py = by;
      racc += best;                        // f32, reference scan order
    }
    float ddx = px - dx0, ddy = py - dy0;
    racc += sqrtf(ddx * ddx + ddy * ddy);  // return-to-depot leg
    gacc += (double)racc;
  }

  // ---- block partial (wave butterfly + cross-wave, deterministic) ----
  {
    double t = (lane16 == 0) ? gacc : 0.0;
#pragma unroll
    for (int m = 1; m < 64; m <<= 1) t += __shfl_xor(t, m);
    if (lane == 0) dred[wv] = t;
  }
  __syncthreads();
  if (tid == 0)
    pdist[blockIdx.x] = dred[0] + dred[1] + dred[2] + dred[3];
}

// ---------------------------------------------------------------------------
// Kernel C: loss finalize (unchanged from r13; passed, absmax 2.5).
// ---------------------------------------------------------------------------
__global__ __launch_bounds__(64) void k_final(
    const double* __restrict__ pdist,    // (1024,)
    const double* __restrict__ lp,       // (64,)
    float* __restrict__ out) {           // (2,)
  int tid = threadIdx.x;
  const double* pb = pdist + tid * WPB;
  double dd = 0.0;
  for (int j = 0; j < WPB; ++j) dd += pb[j];     // fixed order
  float df = (float)dd;
  float lf = (float)lp[tid];
  double m = (double)df;
#pragma unroll
  for (int m2 = 1; m2 < 64; m2 <<= 1) m += __shfl_xor(m, m2);
  double mean = m / 64.0;
  float meanf = (float)mean;
  double li = ((double)df - (double)meanf) * (double)lf;
#pragma unroll
  for (int m2 = 1; m2 < 64; m2 <<= 1) li += __shfl_xor(li, m2);
  if (tid == 0) {
    out[0] = (float)(li / 64.0);
    out[1] = meanf;
  }
}

extern "C" void kernel_launch(void* const* d_in, const int* in_sizes, int n_in,
                              void* d_out, int out_size, void* d_ws, size_t ws_size,
                              hipStream_t stream) {
  const float* logits   = (const float*)d_in[0];  // (64,1001,10)
  const float* coords   = (const float*)d_in[1];  // (64,1001,2)
  const float* demands  = (const float*)d_in[2];  // (64,1001)
  const float* capacity = (const float*)d_in[3];  // (64,)

  uint8_t* ws = (uint8_t*)d_ws;
  double*  pdist  = (double*)(ws);            // 8192 B (1024 doubles)
  double*  lp     = (double*)(ws + 8192);     // 512 B
  uint8_t* assign = (uint8_t*)(ws + 9216);    // 64000 B
  float*   slp    = (float*)(ws + 73216);     // 256000 B

  uint32_t ks0, ks1;
  threefry2x32(0u, 42u, 0u, 0u, &ks0, &ks1);   // fold_in(key(42), 0)

  k_sample<<<dim3(BB * NC * 16 / 256), dim3(256), 0, stream>>>(
      logits, ks0, ks1, assign, slp);
  k_fused<<<dim3(BB * WPB), dim3(256), 0, stream>>>(
      coords, demands, capacity, assign, slp, pdist, lp);
  k_final<<<dim3(1), dim3(64), 0, stream>>>(pdist, lp, (float*)d_out);
}

// Round 15
// 40.084 us; speedup vs baseline: 1.6380x; 1.0019x over previous
//
#include <hip/hip_runtime.h>
#include <stdint.h>

#define BB 64
#define NC 1000       // customers per instance
#define KC 10         // clusters
#define MEMCAP 212    // per-cluster member capacity (mean ~100, 11+ sigma), 16B-aligned rows
#define RCAP 64       // per-cluster route capacity (max possible ~43)

__host__ __device__ inline void threefry2x32(uint32_t k0, uint32_t k1,
                                             uint32_t x0, uint32_t x1,
                                             uint32_t* o0, uint32_t* o1) {
  uint32_t k2 = k0 ^ k1 ^ 0x1BD11BDAu;
  x0 += k0; x1 += k1;
#define TF_R(R) { x0 += x1; x1 = (x1 << (R)) | (x1 >> (32 - (R))); x1 ^= x0; }
  TF_R(13) TF_R(15) TF_R(26) TF_R(6)
  x0 += k1; x1 += k2 + 1u;
  TF_R(17) TF_R(29) TF_R(16) TF_R(24)
  x0 += k2; x1 += k0 + 2u;
  TF_R(13) TF_R(15) TF_R(26) TF_R(6)
  x0 += k0; x1 += k1 + 3u;
  TF_R(17) TF_R(29) TF_R(16) TF_R(24)
  x0 += k1; x1 += k2 + 4u;
  TF_R(13) TF_R(15) TF_R(26) TF_R(6)
  x0 += k2; x1 += k0 + 5u;
#undef TF_R
  *o0 = x0; *o1 = x1;
}

__device__ inline uint32_t rand_bits(uint32_t ks0, uint32_t ks1, uint32_t p) {
  uint32_t a, b; threefry2x32(ks0, ks1, 0u, p, &a, &b); return b;
}

// ---- 16-lane DPP helpers (16-lane group = one DPP row; convergent calls) ----
template <int CTRL>
__device__ __forceinline__ void dpp_min_step(unsigned long long& comb,
                                             float& x, float& y) {
  int lo = (int)(uint32_t)comb;
  int hi = (int)(uint32_t)(comb >> 32);
  int olo = __builtin_amdgcn_update_dpp(lo, lo, CTRL, 0xf, 0xf, false);
  int ohi = __builtin_amdgcn_update_dpp(hi, hi, CTRL, 0xf, 0xf, false);
  int oxi = __builtin_amdgcn_update_dpp(__float_as_int(x), __float_as_int(x),
                                        CTRL, 0xf, 0xf, false);
  int oyi = __builtin_amdgcn_update_dpp(__float_as_int(y), __float_as_int(y),
                                        CTRL, 0xf, 0xf, false);
  unsigned long long o =
      ((unsigned long long)(uint32_t)ohi << 32) | (uint32_t)olo;
  if (o < comb) { comb = o; x = __int_as_float(oxi); y = __int_as_float(oyi); }
}

template <int CTRL>
__device__ __forceinline__ void dpp_max_step(unsigned long long& pk, float& x) {
  int lo = (int)(uint32_t)pk;
  int hi = (int)(uint32_t)(pk >> 32);
  int olo = __builtin_amdgcn_update_dpp(lo, lo, CTRL, 0xf, 0xf, false);
  int ohi = __builtin_amdgcn_update_dpp(hi, hi, CTRL, 0xf, 0xf, false);
  int oxi = __builtin_amdgcn_update_dpp(__float_as_int(x), __float_as_int(x),
                                        CTRL, 0xf, 0xf, false);
  unsigned long long o =
      ((unsigned long long)(uint32_t)ohi << 32) | (uint32_t)olo;
  if (o > pk) { pk = o; x = __int_as_float(oxi); }
}

template <int CTRL>
__device__ __forceinline__ float dpp_fmax(float x) {
  int o = __builtin_amdgcn_update_dpp(__float_as_int(x), __float_as_int(x),
                                      CTRL, 0xf, 0xf, false);
  return fmaxf(x, __int_as_float(o));
}

template <int CTRL>
__device__ __forceinline__ float dpp_fadd(float x) {
  int o = __builtin_amdgcn_update_dpp(__float_as_int(x), __float_as_int(x),
                                      CTRL, 0xf, 0xf, false);
  return x + __int_as_float(o);
}

// ---------------------------------------------------------------------------
// Kernel S: 16 lanes per customer (proven r12-r14, absmax 2.5). Unchanged.
// ---------------------------------------------------------------------------
__global__ __launch_bounds__(256) void k_sample(
    const float* __restrict__ logits,   // (64,1001,10)
    uint32_t ks0, uint32_t ks1,
    uint8_t* __restrict__ assign,       // (64,1000)
    float* __restrict__ slp) {          // (64,1000)
  int gtid = blockIdx.x * 256 + threadIdx.x;   // 1,024,000 = 4000*256
  int cust = gtid >> 4;
  int k = gtid & 15;
  int b = cust / NC, n = cust - b * NC;
  const float TINY = 1.1754943508222875e-38f;
  bool actk = (k < KC);

  float x = actk ? logits[((size_t)b * 1001 + (size_t)(n + 1)) * KC + k]
                 : -INFINITY;
  float v = -INFINITY;
  if (actk) {
    uint32_t bits = rand_bits(ks0, ks1, (uint32_t)cust * (uint32_t)KC + (uint32_t)k);
    float f = __uint_as_float((bits >> 9) | 0x3f800000u) - 1.0f;
    float u = (f > 0.0f) ? f : TINY;
    float g = -logf(-logf(u));
    v = g + x;
  }
  uint32_t uv = __float_as_uint(v);
  uint32_t key = (uv & 0x80000000u) ? ~uv : (uv | 0x80000000u);
  unsigned long long pk =
      ((unsigned long long)key << 32) | (uint32_t)(15 - k);  // ties -> min k
  float bwx = x;
  dpp_max_step<0xB1>(pk, bwx);
  dpp_max_step<0x4E>(pk, bwx);
  dpp_max_step<0x141>(pk, bwx);
  dpp_max_step<0x140>(pk, bwx);
  int best_k = 15 - (int)(pk & 0xFu);

  float xm = x;
  xm = dpp_fmax<0xB1>(xm); xm = dpp_fmax<0x4E>(xm);
  xm = dpp_fmax<0x141>(xm); xm = dpp_fmax<0x140>(xm);

  float es = actk ? expf(x - xm) : 0.0f;
  es = dpp_fadd<0xB1>(es); es = dpp_fadd<0x4E>(es);
  es = dpp_fadd<0x141>(es); es = dpp_fadd<0x140>(es);

  if (k == 0) {
    slp[cust] = (bwx - xm) - logf(es);
    assign[cust] = (uint8_t)best_k;
  }
}

// ---------------------------------------------------------------------------
// Kernel R: ONE WAVE PER CLUSTER, ZERO BARRIERS. Block = 128 thr = 2 waves,
// each wave fully independent (own LDS slice, ballot-compaction, lane-0 split
// walk, 4x16-lane DPP NN). Grid = 64 instances x 6 blocks (blk 0-4: clusters
// 2*blk,2*blk+1; blk 5: lp reduction on wave 0). Same member order / split
// scan / NN winner arithmetic as r14 (bit-identical routes).
// ---------------------------------------------------------------------------
__global__ __launch_bounds__(128) void k_route(
    const float* __restrict__ coords,    // (64,1001,2)
    const float* __restrict__ demands,   // (64,1001)
    const float* __restrict__ capacity,  // (64,)
    const uint8_t* __restrict__ assign,  // (64,1000)
    const float* __restrict__ slp,       // (64,1000)
    double* __restrict__ pdistc,         // (64,10) per-cluster route-dist sums
    double* __restrict__ lp) {           // (64,)
  int b = blockIdx.x / 6;
  int blk = blockIdx.x % 6;
  int tid = threadIdx.x;
  int w = tid >> 6, lane = tid & 63;

  __shared__ float memx[2][MEMCAP], memy[2][MEMCAP], demp[2][MEMCAP];
  __shared__ uint16_t rsw[2][RCAP], rlw[2][RCAP];

  // ---- lp block: wave 0 reduces slp[b]; no LDS, no barriers ----
  if (blk == 5) {
    if (w == 0) {
      const float4* s4 = reinterpret_cast<const float4*>(slp + (size_t)b * NC);
      double acc = 0.0;
#pragma unroll
      for (int t = 0; t < 4; ++t) {
        int idx = t * 64 + lane;
        if (idx < 250) {                 // 250 float4 = 1000 floats exactly
          float4 v = s4[idx];
          acc += (double)v.x + (double)v.y + (double)v.z + (double)v.w;
        }
      }
#pragma unroll
      for (int m = 1; m < 64; m <<= 1) acc += __shfl_xor(acc, m);
      if (lane == 0) lp[b] = acc;
    }
    return;
  }

  int myk = blk * 2 + w;                 // this wave's cluster 0..9
  const float2* cb2 = reinterpret_cast<const float2*>(coords + (size_t)b * 1001 * 2);
  const float* db = demands + (size_t)b * 1001;
  const uint8_t* ab = assign + (size_t)b * NC;
  float cap = capacity[b];
  float dx0, dy0;
  { float2 dep = cb2[0]; dx0 = dep.x; dy0 = dep.y; }

  // ---- zero demp (padding correctness for the float4 split walk) ----
#pragma unroll
  for (int t = 0; t < 4; ++t) {
    int i = t * 64 + lane;
    if (i < MEMCAP) demp[w][i] = 0.0f;
  }

  // ---- ballot compaction: stable member order (round-major = index order) --
  int mcount = 0;
  for (int t = 0; t < 16; ++t) {
    int ci = t * 64 + lane;              // customer 0..1023
    bool p = (ci < NC) && (ab[ci] == (uint8_t)myk);
    unsigned long long mk = __ballot(p);
    int rank = __popcll(mk & ((1ull << lane) - 1ull));
    if (p) {
      int pos = mcount + rank;
      if (pos < MEMCAP) {
        float2 c = cb2[ci + 1];
        memx[w][pos] = c.x;
        memy[w][pos] = c.y;
        demp[w][pos] = db[ci + 1];
      }
    }
    mcount += (int)__popcll(mk);
  }
  int M = (mcount < MEMCAP) ? mcount : MEMCAP;

  // ---- capacity split: lane-0 branch-free float4 walk (r14-proven) ----
  int rcount = 0;
  if (lane == 0 && M > 0) {
    const float4* dp4 = reinterpret_cast<const float4*>(&demp[w][0]);
    float load = 0.0f;
    int cur = 0, r = 0;
    int trips = (M + 3) >> 2;            // dp4[trips] <= dp4[52] in-bounds
    float4 cv = dp4[0];
    for (int t = 0; t < trips; ++t) {
      float4 nv = dp4[t + 1];            // prefetch (zero-padded, in-bounds)
#define SPLIT_E(DV, E)                                                        \
      {                                                                       \
        int j = t * 4 + E;                                                    \
        float d = DV;                                                         \
        if (j == 0) load = d;                                                 \
        else if (load + d > cap) {                                            \
          rsw[w][r] = (uint16_t)cur; rlw[w][r] = (uint16_t)(j - cur);         \
          r++; cur = j; load = d;                                             \
        } else load += d;                /* padding d=0: load<=cap -> no-op */\
      }
      SPLIT_E(cv.x, 0) SPLIT_E(cv.y, 1) SPLIT_E(cv.z, 2) SPLIT_E(cv.w, 3)
#undef SPLIT_E
      cv = nv;
    }
    rsw[w][r] = (uint16_t)cur;
    rlw[w][r] = (uint16_t)(M - cur);
    r++;
    rcount = r;
  }
  rcount = __shfl(rcount, 0);            // wave-uniform route count

  // ---- NN: 4 x 16-lane groups round-robin over this cluster's routes ----
  int lane16 = lane & 15;
  int grp = lane >> 4;                   // 0..3
  double gacc = 0.0;

  for (int r = grp; r < rcount; r += 4) {
    int start = rsw[w][r];
    int L = rlw[w][r];

    float mx0 = 0, my0 = 0, mx1 = 0, my1 = 0, mx2 = 0, my2 = 0, mx3 = 0, my3 = 0;
    uint32_t vis = 0;
#define LOADC(c, MX, MY)                                                      \
    { int s = (c) * 16 + lane16;                                              \
      if (s < L) { MX = memx[w][start + s]; MY = memy[w][start + s]; }        \
      else vis |= (1u << (c)); }
    LOADC(0, mx0, my0) LOADC(1, mx1, my1) LOADC(2, mx2, my2) LOADC(3, mx3, my3)
#undef LOADC

    float px = dx0, py = dy0, racc = 0.0f;
    for (int step = 0; step < L; ++step) {
      float bd = INFINITY; int bc = -1; float bx = 0, by = 0;
#define CAND(c, MX, MY)                                                       \
      if (!(vis & (1u << (c)))) {                                             \
        float ddx = MX - px, ddy = MY - py;                                   \
        float d = sqrtf(ddx * ddx + ddy * ddy);                               \
        if (d < bd) { bd = d; bc = (c); bx = MX; by = MY; }                   \
      }
      CAND(0, mx0, my0) CAND(1, mx1, my1) CAND(2, mx2, my2) CAND(3, mx3, my3)
#undef CAND
      unsigned long long comb = (bc < 0)
          ? ~0ull
          : (((unsigned long long)__float_as_uint(bd)) << 32) |
            (unsigned)(bc * 16 + lane16);
      dpp_min_step<0xB1>(comb, bx, by);
      dpp_min_step<0x4E>(comb, bx, by);
      dpp_min_step<0x141>(comb, bx, by);
      dpp_min_step<0x140>(comb, bx, by);
      int slot = (int)(comb & 0xFFFFFFFFull);
      float best = __uint_as_float((uint32_t)(comb >> 32));
      int src16 = slot & 15, cu = slot >> 4;
      if (src16 == lane16) vis |= (1u << cu);
      px = bx; py = by;
      racc += best;                      // f32, reference scan order
    }
    float ddx = px - dx0, ddy = py - dy0;
    racc += sqrtf(ddx * ddx + ddy * ddy); // return-to-depot leg
    gacc += (double)racc;
  }

  // ---- wave-internal reduction of the 4 group partials ----
  {
    double t2 = (lane16 == 0) ? gacc : 0.0;
#pragma unroll
    for (int m = 1; m < 64; m <<= 1) t2 += __shfl_xor(t2, m);
    if (lane == 0) pdistc[b * KC + myk] = t2;
  }
}

// ---------------------------------------------------------------------------
// Kernel C: loss finalize. Thread i = instance i; sums 10 cluster totals in
// cluster order (matches reference segment order), then shfl loss math.
// ---------------------------------------------------------------------------
__global__ __launch_bounds__(64) void k_final(
    const double* __restrict__ pdistc,   // (64,10)
    const double* __restrict__ lp,       // (64,)
    float* __restrict__ out) {           // (2,)
  int tid = threadIdx.x;
  double dd = 0.0;
#pragma unroll
  for (int k = 0; k < KC; ++k) dd += pdistc[tid * KC + k];
  float df = (float)dd;
  float lf = (float)lp[tid];
  double m = (double)df;
#pragma unroll
  for (int m2 = 1; m2 < 64; m2 <<= 1) m += __shfl_xor(m, m2);
  double mean = m / 64.0;
  float meanf = (float)mean;
  double li = ((double)df - (double)meanf) * (double)lf;
#pragma unroll
  for (int m2 = 1; m2 < 64; m2 <<= 1) li += __shfl_xor(li, m2);
  if (tid == 0) {
    out[0] = (float)(li / 64.0);
    out[1] = meanf;
  }
}

extern "C" void kernel_launch(void* const* d_in, const int* in_sizes, int n_in,
                              void* d_out, int out_size, void* d_ws, size_t ws_size,
                              hipStream_t stream) {
  const float* logits   = (const float*)d_in[0];  // (64,1001,10)
  const float* coords   = (const float*)d_in[1];  // (64,1001,2)
  const float* demands  = (const float*)d_in[2];  // (64,1001)
  const float* capacity = (const float*)d_in[3];  // (64,)

  uint8_t* ws = (uint8_t*)d_ws;
  double*  pdistc = (double*)(ws);            // 5120 B (64*10 doubles)
  double*  lp     = (double*)(ws + 8192);     // 512 B
  uint8_t* assign = (uint8_t*)(ws + 9216);    // 64000 B
  float*   slp    = (float*)(ws + 73216);     // 256000 B

  uint32_t ks0, ks1;
  threefry2x32(0u, 42u, 0u, 0u, &ks0, &ks1);   // fold_in(key(42), 0)

  k_sample<<<dim3(BB * NC * 16 / 256), dim3(256), 0, stream>>>(
      logits, ks0, ks1, assign, slp);
  k_route<<<dim3(BB * 6), dim3(128), 0, stream>>>(
      coords, demands, capacity, assign, slp, pdistc, lp);
  k_final<<<dim3(1), dim3(64), 0, stream>>>(pdistc, lp, (float*)d_out);
}